// Round 3
// baseline (259.662 us; speedup 1.0000x reference)
//
#include <hip/hip_runtime.h>
#include <hip/hip_bf16.h>
#include <stdint.h>

// EncoderLayer: B=8 N=1024 D=512 H=8 Dh=64 FF=2048
#define B_   8
#define N_   1024
#define DM   512
#define H_   8
#define DFF  2048
#define ROWS (B_ * N_)          // 8192
#define QKV_LD (3 * DM)         // 1536
#define LOG2E 1.4426950408889634f
#define SCL  (0.125f * LOG2E)   // att scale 1/8 folded into exp2

typedef __bf16 bf16x8 __attribute__((ext_vector_type(8)));
typedef float  f32x4  __attribute__((ext_vector_type(4)));

__device__ __forceinline__ void gld_lds16(const void* g, void* l) {
  __builtin_amdgcn_global_load_lds((__attribute__((address_space(1))) void*)g,
                                   (__attribute__((address_space(3))) void*)l, 16, 0, 0);
}

__device__ __forceinline__ unsigned short bfb(float x) {
  __bf16 h = (__bf16)x;
  unsigned short u;
  __builtin_memcpy(&u, &h, 2);
  return u;
}

// ---------------- prep: x_q = q+pos, x_k = k+pos, x_v = v  (f32 -> bf16) ----
__global__ __launch_bounds__(256) void prep_x(
    const float* __restrict__ q, const float* __restrict__ k,
    const float* __restrict__ v, const float* __restrict__ pos,
    __bf16* __restrict__ xq, __bf16* __restrict__ xk, __bf16* __restrict__ xv) {
  int i = blockIdx.x * 256 + threadIdx.x;      // float4 group
  float4 pv = ((const float4*)pos)[i];
  float4 qv = ((const float4*)q)[i];
  float4 kv = ((const float4*)k)[i];
  float4 vv = ((const float4*)v)[i];
  ushort4 o;
  o.x = bfb(qv.x + pv.x); o.y = bfb(qv.y + pv.y); o.z = bfb(qv.z + pv.z); o.w = bfb(qv.w + pv.w);
  ((ushort4*)xq)[i] = o;
  o.x = bfb(kv.x + pv.x); o.y = bfb(kv.y + pv.y); o.z = bfb(kv.z + pv.z); o.w = bfb(kv.w + pv.w);
  ((ushort4*)xk)[i] = o;
  o.x = bfb(vv.x); o.y = bfb(vv.y); o.z = bfb(vv.z); o.w = bfb(vv.w);
  ((ushort4*)xv)[i] = o;
}

// ---------------- all weight transposes in ONE launch -----------------------
__global__ __launch_bounds__(256) void transpose_all(
    const float* __restrict__ Wq, const float* __restrict__ Wk,
    const float* __restrict__ Wv, const float* __restrict__ Wo,
    const float* __restrict__ W1, const float* __restrict__ W2,
    __bf16* __restrict__ WqkvT, __bf16* __restrict__ WoT,
    __bf16* __restrict__ W1T, __bf16* __restrict__ W2T) {
  __shared__ float tl[32][33];
  int idx = blockIdx.x;
  const float* src; __bf16* dst; int K, N, t;
  if (idx < 768) {                       // Wq,Wk,Wv -> WqkvT (stacked)
    src = idx < 256 ? Wq : (idx < 512 ? Wk : Wv);
    dst = WqkvT + (size_t)(idx >> 8) * 512 * 512;
    K = 512; N = 512; t = idx & 255;
  } else if (idx < 1024) { src = Wo; dst = WoT;  K = 512;  N = 512;  t = idx - 768; }
  else if (idx < 2048)   { src = W1; dst = W1T;  K = 512;  N = 2048; t = idx - 1024; }
  else                   { src = W2; dst = W2T;  K = 2048; N = 512;  t = idx - 2048; }
  int tiles_n = N >> 5;
  int tn = t & (tiles_n - 1), tk = t / tiles_n;
  int n0 = tn * 32, k0 = tk * 32;
  int x = threadIdx.x & 31, y4 = threadIdx.x >> 5;
  #pragma unroll
  for (int j = y4; j < 32; j += 8) tl[j][x] = src[(size_t)(k0 + j) * N + n0 + x];
  __syncthreads();
  #pragma unroll
  for (int j = y4; j < 32; j += 8)
    dst[(size_t)(n0 + j) * K + k0 + x] = (__bf16)tl[x][j];
}

// ---------------- V^T: Vt[b,h,d,n] = QKV[b*N+n][1024 + h*64 + d] ------------
__global__ __launch_bounds__(256) void transpose_v(
    const __bf16* __restrict__ QKV, __bf16* __restrict__ Vt) {
  __shared__ __bf16 t[32][33];
  int bh = blockIdx.y;                 // b*8+h
  int b = bh >> 3, h = bh & 7;
  int tn = blockIdx.x >> 1;            // n tile (0..31)
  int td = blockIdx.x & 1;             // d tile (0..1)
  int x = threadIdx.x & 31, y4 = threadIdx.x >> 5;
  #pragma unroll
  for (int j = y4; j < 32; j += 8)
    t[j][x] = QKV[(size_t)(b * N_ + tn * 32 + j) * QKV_LD + 2 * DM + h * 64 + td * 32 + x];
  __syncthreads();
  #pragma unroll
  for (int j = y4; j < 32; j += 8)
    Vt[(size_t)(bh * 64 + td * 32 + j) * N_ + tn * 32 + x] = t[x][j];
}

// ---------------- GEMM: C[M,N] = A[M,K] @ BT[N,K]^T + bias ------------------
// m97 structure. EPI: 0 = bf16 store, 1 = bf16 relu store.
template <int EPI>
__global__ __launch_bounds__(256, 2) void gemm_bt(
    const __bf16* __restrict__ A0, const __bf16* __restrict__ A1, const __bf16* __restrict__ A2,
    const __bf16* __restrict__ BT,
    const float* __restrict__ bias0, const float* __restrict__ bias1, const float* __restrict__ bias2,
    void* __restrict__ Cp, int M, int N, int K, int nsplit) {
  __shared__ __align__(16) __bf16 As[128 * 64];
  __shared__ __align__(16) __bf16 Bs[128 * 64];
  int tid = threadIdx.x, lane = tid & 63;
  int wave = tid >> 6;
  int wr = (wave >> 1) * 64, wc = (wave & 1) * 64;

  int gx = N >> 7;
  int nwg = gridDim.x;
  int cpx = nwg >> 3;                       // nwg % 8 == 0 for all our shapes
  int swz = (blockIdx.x & 7) * cpx + (blockIdx.x >> 3);
  int bx = swz % gx, by = swz / gx;
  int row0 = by << 7, col0 = bx << 7;

  int asel = col0 / nsplit;
  const __bf16* A = asel == 0 ? A0 : (asel == 1 ? A1 : A2);
  const float* bias = asel == 0 ? bias0 : (asel == 1 ? bias1 : bias2);

  f32x4 acc[4][4] = {};

  for (int kt = 0; kt < K; kt += 64) {
    #pragma unroll
    for (int i = 0; i < 4; ++i) {
      int t = i * 256 + tid;
      int r = t >> 3, cL = t & 7;
      int cS = cL ^ (r & 7);                // inverse swizzle on global source
      gld_lds16(A + (size_t)(row0 + r) * K + kt + cS * 8, As + t * 8);
      gld_lds16(BT + (size_t)(col0 + r) * K + kt + cS * 8, Bs + t * 8);
    }
    __syncthreads();
    #pragma unroll
    for (int ks = 0; ks < 2; ++ks) {
      bf16x8 af[4], bfr[4];
      #pragma unroll
      for (int m = 0; m < 4; ++m) {
        int r = wr + m * 16 + (lane & 15);
        int c = (ks * 4 + (lane >> 4)) ^ (r & 7);
        af[m] = *(const bf16x8*)(As + r * 64 + c * 8);
      }
      #pragma unroll
      for (int n = 0; n < 4; ++n) {
        int r = wc + n * 16 + (lane & 15);
        int c = (ks * 4 + (lane >> 4)) ^ (r & 7);
        bfr[n] = *(const bf16x8*)(Bs + r * 64 + c * 8);
      }
      #pragma unroll
      for (int m = 0; m < 4; ++m)
        #pragma unroll
        for (int n = 0; n < 4; ++n)
          acc[m][n] = __builtin_amdgcn_mfma_f32_16x16x32_bf16(af[m], bfr[n], acc[m][n], 0, 0, 0);
    }
    __syncthreads();
  }

  int rb = row0 + wr + ((lane >> 4) << 2);
  int cb = col0 + wc + (lane & 15);
  #pragma unroll
  for (int n = 0; n < 4; ++n) {
    int c = cb + n * 16;
    float bv = bias[c % nsplit];
    #pragma unroll
    for (int m = 0; m < 4; ++m) {
      #pragma unroll
      for (int j = 0; j < 4; ++j) {
        int r = rb + m * 16 + j;
        float v = acc[m][n][j] + bv;
        if (EPI == 1) v = fmaxf(v, 0.f);
        ((__bf16*)Cp)[(size_t)r * N + c] = (__bf16)v;
      }
    }
  }
}

// ---------------- GEMM + residual + LayerNorm fused -------------------------
// C = LN(resid + A@BT^T + bias). BM=32, BN=512 (full row per block), 4 waves
// each 32x128. grid = ROWS/32 = 256. LN stats: 16-lane shfl + 4-wave LDS red.
// WRITE_BF: also emit bf16 copy (for FF1 input).
template <int WRITE_BF>
__global__ __launch_bounds__(256, 2) void gemm_ln(
    const __bf16* __restrict__ A, const __bf16* __restrict__ BT,
    const float* __restrict__ bias, const float* __restrict__ resid,
    const float* __restrict__ gw, const float* __restrict__ bw,
    float* __restrict__ outf, __bf16* __restrict__ outb, int K) {
  __shared__ __align__(16) __bf16 As[32 * 64];
  __shared__ __align__(16) __bf16 Bs[512 * 64];
  __shared__ float redS[4][32], redQ[4][32];
  int tid = threadIdx.x, lane = tid & 63, wave = tid >> 6;
  const int g = lane >> 4, u = lane & 15;
  int row0 = blockIdx.x * 32;
  int wc = wave * 128;

  f32x4 acc[2][8] = {};

  for (int kt = 0; kt < K; kt += 64) {
    {
      int r = tid >> 3, cL = tid & 7, cS = cL ^ (r & 7);
      gld_lds16(A + (size_t)(row0 + r) * K + kt + cS * 8, As + tid * 8);
    }
    #pragma unroll
    for (int i = 0; i < 16; ++i) {
      int t = i * 256 + tid;
      int r = t >> 3, cL = t & 7, cS = cL ^ (r & 7);
      gld_lds16(BT + (size_t)r * K + kt + cS * 8, Bs + t * 8);
    }
    __syncthreads();
    #pragma unroll
    for (int ks = 0; ks < 2; ++ks) {
      bf16x8 af[2], bfr[8];
      #pragma unroll
      for (int m = 0; m < 2; ++m) {
        int r = m * 16 + u;
        int c = (ks * 4 + g) ^ (r & 7);
        af[m] = *(const bf16x8*)(As + r * 64 + c * 8);
      }
      #pragma unroll
      for (int n = 0; n < 8; ++n) {
        int r = wc + n * 16 + u;
        int c = (ks * 4 + g) ^ (r & 7);
        bfr[n] = *(const bf16x8*)(Bs + r * 64 + c * 8);
      }
      #pragma unroll
      for (int m = 0; m < 2; ++m)
        #pragma unroll
        for (int n = 0; n < 8; ++n)
          acc[m][n] = __builtin_amdgcn_mfma_f32_16x16x32_bf16(af[m], bfr[n], acc[m][n], 0, 0, 0);
    }
    __syncthreads();
  }

  // v = acc + bias + resid; accumulate row partial sums over this wave's panel
  float ps[2][4] = {}, pq[2][4] = {};
  #pragma unroll
  for (int m = 0; m < 2; ++m)
    #pragma unroll
    for (int n = 0; n < 8; ++n) {
      int c = wc + n * 16 + u;
      float bv = bias[c];
      #pragma unroll
      for (int j = 0; j < 4; ++j) {
        int r = row0 + m * 16 + g * 4 + j;
        float v = acc[m][n][j] + bv + resid[(size_t)r * DM + c];
        acc[m][n][j] = v;
        ps[m][j] += v;
        pq[m][j] += v * v;
      }
    }
  #pragma unroll
  for (int o = 1; o < 16; o <<= 1)
    #pragma unroll
    for (int m = 0; m < 2; ++m)
      #pragma unroll
      for (int j = 0; j < 4; ++j) {
        ps[m][j] += __shfl_xor(ps[m][j], o);
        pq[m][j] += __shfl_xor(pq[m][j], o);
      }
  if (u == 0) {
    #pragma unroll
    for (int m = 0; m < 2; ++m)
      #pragma unroll
      for (int j = 0; j < 4; ++j) {
        redS[wave][m * 16 + g * 4 + j] = ps[m][j];
        redQ[wave][m * 16 + g * 4 + j] = pq[m][j];
      }
  }
  __syncthreads();
  float mu[2][4], rstd[2][4];
  #pragma unroll
  for (int m = 0; m < 2; ++m)
    #pragma unroll
    for (int j = 0; j < 4; ++j) {
      int rr = m * 16 + g * 4 + j;
      float s = redS[0][rr] + redS[1][rr] + redS[2][rr] + redS[3][rr];
      float q2 = redQ[0][rr] + redQ[1][rr] + redQ[2][rr] + redQ[3][rr];
      float m_ = s * (1.f / DM);
      float var = q2 * (1.f / DM) - m_ * m_;
      mu[m][j] = m_;
      rstd[m][j] = rsqrtf(var + 1e-5f);
    }
  #pragma unroll
  for (int m = 0; m < 2; ++m)
    #pragma unroll
    for (int n = 0; n < 8; ++n) {
      int c = wc + n * 16 + u;
      float gv = gw[c], bv2 = bw[c];
      #pragma unroll
      for (int j = 0; j < 4; ++j) {
        int r = row0 + m * 16 + g * 4 + j;
        float y = (acc[m][n][j] - mu[m][j]) * rstd[m][j] * gv + bv2;
        outf[(size_t)r * DM + c] = y;
        if (WRITE_BF) outb[(size_t)r * DM + c] = (__bf16)y;
      }
    }
}

// ---------------- fused attention (2-phase pipelined) ------------------------
// softmax(log(clip(w)) + s) == normalize(clip(w) * exp(s)). Double-buffered
// K/V/rgw staging with counted vmcnt(8) (T3+T4), setprio around MFMA (T5).
__global__ __launch_bounds__(256, 2) void attn_kernel(
    const __bf16* __restrict__ QKV, const __bf16* __restrict__ Vt,
    const float* __restrict__ rgw, __bf16* __restrict__ O) {
  __shared__ __align__(16) __bf16 Qs[64 * 64];
  __shared__ __align__(16) __bf16 Ks[2][64 * 64];
  __shared__ __align__(16) __bf16 Vs[2][64 * 64];
  __shared__ __align__(16) float  Ws[2][64 * 64];
  __shared__ __align__(16) __bf16 Ps[4][16 * 64];

  int tid = threadIdx.x, lane = tid & 63, wave = tid >> 6;
  int flat = blockIdx.x;
  int qt = flat & 15, h = (flat >> 4) & 7, b = flat >> 7;
  int q0 = qt * 64;
  const int g = lane >> 4, u = lane & 15;
  size_t rgw_tile = ((size_t)(b * H_ + h) * N_ + (size_t)q0) * N_;

#define STAGE_ATTN(KD, VD, WD, KT)                                             \
  {                                                                            \
    _Pragma("unroll")                                                          \
    for (int i = 0; i < 2; ++i) {                                              \
      int t = i * 256 + tid;                                                   \
      int r = t >> 3, cL = t & 7, cS = cL ^ (r & 7);                           \
      gld_lds16(QKV + (size_t)(b * N_ + (KT) + r) * QKV_LD + DM + h * 64 + cS * 8, (KD) + t * 8); \
      gld_lds16(Vt + (size_t)((b * H_ + h) * 64 + r) * N_ + (KT) + cS * 8, (VD) + t * 8);         \
    }                                                                          \
    _Pragma("unroll")                                                          \
    for (int i = 0; i < 4; ++i) {                                              \
      int C = i * 256 + tid;                                                   \
      int R = C >> 4;                                                          \
      int cs0 = (C & 15) << 2;                                                 \
      int gp = (R >> 2) & 3;                                                   \
      int sc = cs0 ^ (gp << 2) ^ ((gp & 1) << 4);                              \
      gld_lds16(rgw + rgw_tile + (size_t)R * N_ + (KT) + sc, (WD) + C * 4);    \
    }                                                                          \
  }

  // stage Q tile + tile 0
  #pragma unroll
  for (int i = 0; i < 2; ++i) {
    int t = i * 256 + tid;
    int r = t >> 3, cL = t & 7, cS = cL ^ (r & 7);
    gld_lds16(QKV + (size_t)(b * N_ + q0 + r) * QKV_LD + h * 64 + cS * 8, Qs + t * 8);
  }
  STAGE_ATTN(Ks[0], Vs[0], Ws[0], 0)
  asm volatile("s_waitcnt vmcnt(8)" ::: "memory");   // Q landed; tile0 in flight
  __builtin_amdgcn_s_barrier();

  bf16x8 qf[2];
  {
    int r = wave * 16 + u;
    #pragma unroll
    for (int ks = 0; ks < 2; ++ks) {
      int c = (ks * 4 + g) ^ (r & 7);
      qf[ks] = *(const bf16x8*)(Qs + r * 64 + c * 8);
    }
  }

  float l[4] = {0.f, 0.f, 0.f, 0.f};
  f32x4 oacc[4] = {};
  __bf16* pw = &Ps[wave][0];

  for (int t16 = 0; t16 < 16; ++t16) {
    int cur = t16 & 1;
    if (t16 < 15) {
      STAGE_ATTN(Ks[cur ^ 1], Vs[cur ^ 1], Ws[cur ^ 1], (t16 + 1) * 64)
      asm volatile("s_waitcnt vmcnt(8)" ::: "memory");  // tile t landed
    } else {
      asm volatile("s_waitcnt vmcnt(0)" ::: "memory");
    }
    __builtin_amdgcn_s_barrier();

    const __bf16* ksb = Ks[cur];
    const __bf16* vsb = Vs[cur];
    const float*  wsb = Ws[cur];

    // S = Q @ K^T
    f32x4 s[4] = {};
    __builtin_amdgcn_s_setprio(1);
    #pragma unroll
    for (int ks = 0; ks < 2; ++ks) {
      #pragma unroll
      for (int n = 0; n < 4; ++n) {
        int r = n * 16 + u;
        int c = (ks * 4 + g) ^ (r & 7);
        bf16x8 kf = *(const bf16x8*)(ksb + r * 64 + c * 8);
        s[n] = __builtin_amdgcn_mfma_f32_16x16x32_bf16(qf[ks], kf, s[n], 0, 0, 0);
      }
    }
    __builtin_amdgcn_s_setprio(0);

    // p = clip(w) * exp(s); per-lane row-sum partials
    float p[4][4];
    #pragma unroll
    for (int n = 0; n < 4; ++n)
      #pragma unroll
      for (int j = 0; j < 4; ++j) {
        int R = wave * 16 + g * 4 + j;
        float w = wsb[R * 64 + ((n * 16 + u) ^ (g << 2) ^ ((g & 1) << 4))];
        p[n][j] = fmaxf(w, 1e-6f) * exp2f(s[n][j] * SCL);
        l[j] += p[n][j];
      }

    // P: C-layout -> swizzled per-wave LDS
    #pragma unroll
    for (int n = 0; n < 4; ++n)
      #pragma unroll
      for (int j = 0; j < 4; ++j) {
        int r = g * 4 + j;
        int col = n * 16 + u;
        int cS = (col >> 3) ^ (r & 7);
        pw[r * 64 + cS * 8 + (col & 7)] = (__bf16)p[n][j];
      }

    // O += P @ V
    __builtin_amdgcn_s_setprio(1);
    #pragma unroll
    for (int ks = 0; ks < 2; ++ks) {
      int cp = (ks * 4 + g) ^ (u & 7);
      bf16x8 pa = *(const bf16x8*)(pw + u * 64 + cp * 8);
      #pragma unroll
      for (int n = 0; n < 4; ++n) {
        int r = n * 16 + u;
        int c = (ks * 4 + g) ^ (r & 7);
        bf16x8 vb = *(const bf16x8*)(vsb + r * 64 + c * 8);
        oacc[n] = __builtin_amdgcn_mfma_f32_16x16x32_bf16(pa, vb, oacc[n], 0, 0, 0);
      }
    }
    __builtin_amdgcn_s_setprio(0);
    __builtin_amdgcn_s_barrier();
  }
#undef STAGE_ATTN

  #pragma unroll
  for (int o = 1; o < 16; o <<= 1)
    #pragma unroll
    for (int j = 0; j < 4; ++j) l[j] += __shfl_xor(l[j], o);

  int orow = b * N_ + q0 + wave * 16 + g * 4;
  int ocol = h * 64 + u;
  #pragma unroll
  for (int j = 0; j < 4; ++j) {
    float inv = 1.f / l[j];
    #pragma unroll
    for (int n = 0; n < 4; ++n)
      O[(size_t)(orow + j) * DM + ocol + n * 16] = (__bf16)(oacc[n][j] * inv);
  }
}

// ---------------- launch -----------------------------------------------------
extern "C" void kernel_launch(void* const* d_in, const int* in_sizes, int n_in,
                              void* d_out, int out_size, void* d_ws, size_t ws_size,
                              hipStream_t stream) {
  const float* queries = (const float*)d_in[0];
  const float* keys    = (const float*)d_in[1];
  const float* values  = (const float*)d_in[2];
  const float* rgw     = (const float*)d_in[3];
  const float* pos     = (const float*)d_in[4];
  const float* Wq = (const float*)d_in[5];
  const float* bq = (const float*)d_in[6];
  const float* Wk = (const float*)d_in[7];
  const float* bk = (const float*)d_in[8];
  const float* Wv = (const float*)d_in[9];
  const float* bv = (const float*)d_in[10];
  const float* Wo = (const float*)d_in[11];
  const float* bo = (const float*)d_in[12];
  const float* ln1g = (const float*)d_in[13];
  const float* ln1b = (const float*)d_in[14];
  const float* W1 = (const float*)d_in[15];
  const float* b1 = (const float*)d_in[16];
  const float* W2 = (const float*)d_in[17];
  const float* b2 = (const float*)d_in[18];
  const float* ln2g = (const float*)d_in[19];
  const float* ln2b = (const float*)d_in[20];
  float* out = (float*)d_out;

  char* ws = (char*)d_ws;
  const size_t SZX = (size_t)ROWS * DM * 2;        // 8 MB (bf16 8192x512)
  __bf16* Xq    = (__bf16*)(ws);
  __bf16* Xk    = (__bf16*)(ws + SZX);
  __bf16* Xv    = (__bf16*)(ws + 2 * SZX);
  __bf16* WqkvT = (__bf16*)(ws + 3 * SZX);                       // 1536x512
  __bf16* WoT   = (__bf16*)(ws + 3 * SZX + 1572864);             // 512x512
  __bf16* W1T   = (__bf16*)(ws + 3 * SZX + 2097152);             // 2048x512
  __bf16* W2T   = (__bf16*)(ws + 3 * SZX + 4194304);             // 512x2048
  __bf16* QKV   = (__bf16*)(ws + 3 * SZX + 6291456);             // 8192x1536
  __bf16* Vt    = (__bf16*)(ws + 3 * SZX + 6291456 + 3 * SZX);   // (B,H,64,N)
  __bf16* Oat   = (__bf16*)(ws + 3 * SZX + 6291456 + 4 * SZX);
  __bf16* ff1   = (__bf16*)(ws + 3 * SZX + 6291456 + 5 * SZX);   // 8192x2048
  // aliases over dead regions:
  float*  attoutf = (float*)QKV;    // f32 8192x512 over QKV (dead after attn)
  __bf16* attoutb = Xv;             // bf16 over Xv (dead after QKV GEMM)

  prep_x<<<ROWS * DM / 4 / 256, 256, 0, stream>>>(queries, keys, values, pos, Xq, Xk, Xv);
  transpose_all<<<3072, 256, 0, stream>>>(Wq, Wk, Wv, Wo, W1, W2, WqkvT, WoT, W1T, W2T);

  gemm_bt<0><<<(ROWS / 128) * (QKV_LD / 128), 256, 0, stream>>>(
      Xq, Xk, Xv, WqkvT, bq, bk, bv, QKV, ROWS, QKV_LD, DM, DM);

  transpose_v<<<dim3(64, B_ * H_), 256, 0, stream>>>(QKV, Vt);

  attn_kernel<<<B_ * H_ * (N_ / 64), 256, 0, stream>>>(QKV, Vt, rgw, Oat);

  // Wo + residual(queries) + LN1 -> attoutf (f32) & attoutb (bf16)
  gemm_ln<1><<<ROWS / 32, 256, 0, stream>>>(
      Oat, WoT, bo, queries, ln1g, ln1b, attoutf, attoutb, DM);

  gemm_bt<1><<<(ROWS / 128) * (DFF / 128), 256, 0, stream>>>(
      attoutb, attoutb, attoutb, W1T, b1, b1, b1, ff1, ROWS, DFF, DM, DFF);

  // FF2 + residual(attoutf) + LN2 -> out (f32)
  gemm_ln<0><<<ROWS / 32, 256, 0, stream>>>(
      ff1, W2T, b2, attoutf, ln2g, ln2b, out, nullptr, DFF);
}